// Round 7
// baseline (709.752 us; speedup 1.0000x reference)
//
#include <hip/hip_runtime.h>
#include <stdint.h>

typedef __bf16 bf16_t;
typedef __bf16 bf16x8 __attribute__((ext_vector_type(8)));
typedef float floatx4 __attribute__((ext_vector_type(4)));
typedef float f32x4 __attribute__((ext_vector_type(4)));  // for nontemporal builtins

#define N_ROWS 16384
#define D_IN   2048
#define D_OUT  2048
#define EPSF   1e-6f
#define TINYF  1e-15f

// GEMM geometry: 256x256 tile, BK=32, 8 waves (512 thr), 3-deep LDS rotation
#define BM 256
#define BN 256
#define BK 32
#define NT 192  // 3 precision segments * (2048/32) k-tiles

// async global->LDS, 16B/lane; LDS base wave-uniform, lane*16 implicit
__device__ __forceinline__ void load_lds16(const void* g, void* l) {
    __builtin_amdgcn_global_load_lds(
        (const __attribute__((address_space(1))) unsigned int*)(const unsigned int*)g,
        (__attribute__((address_space(3))) unsigned int*)(unsigned int*)l,
        16, 0, 0);
}

// ---------- Kernel 0: split W (f32) into bf16 hi/lo planes ----------
__global__ __launch_bounds__(256) void pvfc_wsplit(
    const float* __restrict__ W, bf16_t* __restrict__ Wh, bf16_t* __restrict__ Wl)
{
    const size_t i = ((size_t)blockIdx.x * 256 + threadIdx.x) * 8;
    f32x4 a = *(const f32x4*)(W + i);
    f32x4 c = *(const f32x4*)(W + i + 4);
    float v[8] = {a.x, a.y, a.z, a.w, c.x, c.y, c.z, c.w};
    bf16x8 hv, lv;
#pragma unroll
    for (int j = 0; j < 8; ++j) {
        const bf16_t h = (bf16_t)v[j];
        hv[j] = h;
        lv[j] = (bf16_t)(v[j] - (float)h);
    }
    *(bf16x8*)(Wh + i) = hv;
    *(bf16x8*)(Wl + i) = lv;
}

// ---------- Kernel 1: v = asinh(||x||)/||x|| * x, split into bf16 hi/lo ----------
// A layout: [rows][4096] bf16 : cols 0..2047 = v_hi, 2048..4095 = v_lo
__global__ __launch_bounds__(256) void pvfc_prologue(
    const float* __restrict__ x, bf16_t* __restrict__ Ap)
{
    __shared__ float red[4];
    const int row = blockIdx.x, tid = threadIdx.x;
    const int lane = tid & 63, wave = tid >> 6;

    const float* xr = x + (size_t)row * D_IN + tid * 8;
    f32x4 a = __builtin_nontemporal_load((const f32x4*)xr);
    f32x4 c = __builtin_nontemporal_load((const f32x4*)(xr + 4));
    float v[8] = {a.x, a.y, a.z, a.w, c.x, c.y, c.z, c.w};

    float s = 0.f;
#pragma unroll
    for (int i = 0; i < 8; ++i) s += v[i] * v[i];
#pragma unroll
    for (int off = 32; off > 0; off >>= 1) s += __shfl_down(s, off, 64);
    if (lane == 0) red[wave] = s;
    __syncthreads();
    const float s2  = red[0] + red[1] + red[2] + red[3];
    const float nrm = sqrtf(s2);
    const float coef = asinhf(nrm) / fmaxf(nrm, EPSF);

    bf16x8 hv, lv;
#pragma unroll
    for (int j = 0; j < 8; ++j) {
        const float vi = coef * v[j];
        const bf16_t h = (bf16_t)vi;
        hv[j] = h;
        lv[j] = (bf16_t)(vi - (float)h);
    }
    bf16_t* ar = Ap + (size_t)row * (2 * D_IN);
    *(bf16x8*)(ar + tid * 8)         = hv;   // cached: gemm re-reads A via L3
    *(bf16x8*)(ar + D_IN + tid * 8)  = lv;
}

// ---------- Kernel 2: U = Ah.Wh^T + Al.Wh^T + Ah.Wl^T ----------
// Cross-tile register pipeline + 3-buffer LDS rotation (BK=32), one barrier per
// tile (round-5 structure), NOW with the chunk-XOR bank swizzle restored:
// round-6 counters proved BK=32 rows are NOT conflict-free (SQ_LDS_BANK_CONFLICT
// 3.8e7, 8-way: 16 lanes/quad-group hit banks 16*(row&1)+4*quad only).
// Swizzle p = c ^ ((row>>1)&3) gives banks 16*(row&1)+4*(q^((m16>>1)&3)):
// every bank-quad x2 lanes = 2-way = free (m136). Applied BOTH sides (rule #21):
// linear LDS dest + pre-swizzled global source col; swizzled ds_read addr.
#define BAR __builtin_amdgcn_s_barrier()
#define SCHED_FENCE __builtin_amdgcn_sched_barrier(0)
#define WAIT_LGKM0 do { asm volatile("s_waitcnt lgkmcnt(0)" ::: "memory"); \
                        __builtin_amdgcn_sched_barrier(0); } while (0)
#define WAIT_VM0   do { asm volatile("s_waitcnt vmcnt(0)" ::: "memory");   \
                        __builtin_amdgcn_sched_barrier(0); } while (0)

// read 4 A-frags (row-blocks h*4..h*4+3) of the NEXT tile from LDS buf brd
// physical chunk = quad ^ ((row>>1)&3); row base multiple of 16 -> key = (m16>>1)&3
#define READ_A4(AF, brd, h)                                                    \
    _Pragma("unroll")                                                          \
    for (int i = 0; i < 4; ++i) {                                              \
        const int mi = (h) * 4 + i;                                            \
        AF[mi] = *(const bf16x8*)&As3[(brd) * 8192 +                           \
                    (wm * 128 + mi * 16 + m16) * 32 + ((quad ^ swk) * 8)];     \
    }
// read 4 B-frags of the NEXT tile
#define READ_B4(BF, brd)                                                       \
    _Pragma("unroll")                                                          \
    for (int j = 0; j < 4; ++j)                                                \
        BF[j] = *(const bf16x8*)&Bs3[(brd) * 8192 +                            \
                    (wn * 64 + j * 16 + m16) * 32 + ((quad ^ swk) * 8)];
// 8 MFMA: row-blocks g*2..g*2+1 x all 4 col-blocks, CURRENT frags
#define MFMA_G(AF, BF, g)                                                      \
    do {                                                                       \
        __builtin_amdgcn_s_setprio(1);                                         \
        _Pragma("unroll")                                                      \
        for (int i = 0; i < 2; ++i)                                            \
            _Pragma("unroll")                                                  \
            for (int j = 0; j < 4; ++j)                                        \
                acc[(g) * 2 + i][j] = __builtin_amdgcn_mfma_f32_16x16x32_bf16( \
                    AF[(g) * 2 + i], BF[j], acc[(g) * 2 + i][j], 0, 0, 0);     \
        __builtin_amdgcn_s_setprio(0);                                         \
    } while (0)

// body for tile T: compute from (AC,BC); read tile T+1 frags into (AN,BN_) from
// buf brd=(T+1)%3; stage tile stT=T+2 into buf bst=(T+2)%3. One barrier.
// Hazards: stage(T+2->bst): bst's last ds_reads were in body T-2, drained at
// T-1's top lgkm0, >=1 barrier before this stage. RAW: stage(T+1) drained by
// body T-1's vmcnt(0)+BAR before reads in body T.
#define BODY(AC, BC, AN, BN_, brd, bst, stT)                                   \
    do {                                                                       \
        WAIT_LGKM0;                 /* prev body's 12 frag reads: long landed */\
        stage_tile(stT, bst);       /* 4 vmem, drained at body end */          \
        SCHED_FENCE;                                                           \
        READ_A4(AN, brd, 0); MFMA_G(AC, BC, 0); SCHED_FENCE;                   \
        READ_A4(AN, brd, 1); MFMA_G(AC, BC, 1); SCHED_FENCE;                   \
        READ_B4(BN_, brd);   MFMA_G(AC, BC, 2); SCHED_FENCE;                   \
        MFMA_G(AC, BC, 3);                                                     \
        WAIT_VM0;                                                              \
        BAR;                                                                   \
    } while (0)

__global__ __launch_bounds__(512, 2) void pvfc_gemm(
    const bf16_t* __restrict__ A,   // [rows][4096] hi|lo
    const bf16_t* __restrict__ Wh, const bf16_t* __restrict__ Wl, // [2048][2048]
    float* __restrict__ U)          // [rows][2048] f32
{
    __shared__ __align__(16) bf16_t As3[3 * BM * BK];  // 48 KiB
    __shared__ __align__(16) bf16_t Bs3[3 * BN * BK];  // 48 KiB

    const int tid  = threadIdx.x;
    const int wave = tid >> 6, lane = tid & 63;
    const int bid  = blockIdx.x;
    const int colBase = (bid & 7) * BN;   // bid%8 == XCD: W panel L2-resident
    const int rowBase = (bid >> 3) * BM;

    const int wm = wave >> 2, wn = wave & 3;   // 2x4 wave grid, 128x64/wave
    const int m16 = lane & 15, quad = lane >> 4;
    const int swk = (m16 >> 1) & 3;            // read-side xor key

    floatx4 acc[8][4];
    bf16x8 af0[8], af1[8], bf0[4], bf1[4];     // double-buffered fragments
    const floatx4 z = {0.f, 0.f, 0.f, 0.f};
#pragma unroll
    for (int i = 0; i < 8; ++i)
#pragma unroll
        for (int j = 0; j < 4; ++j) acc[i][j] = z;

    // stage one BK=32 tile (A 16KB + B 16KB) into LDS buf b; LDS dest linear,
    // source column pre-swizzled: thread writes physical chunk tid&3 of row
    // tid>>2 -> logical chunk (tid&3)^((row>>1)&3), row>>1 = tid>>3.
    // (+128-row half: same key, since 128>>1 = 64 == 0 mod 4.)
    const int sRow = tid >> 2;                                  // 0..127
    const int sC   = (((tid & 3) ^ ((tid >> 3) & 3)) * 8);      // swizzled col
    auto stage_tile = [&](int tile, int b) {
        const int tt  = tile < NT ? tile : NT - 1;   // tail clamp: stages into a
        const int seg = tt >> 6;                     // buffer never read again
        const int k0  = (tt & 63) * BK;
        const size_t aOff = (size_t)((seg == 1) ? D_IN : 0) + k0;
        const bf16_t* Wp  = (seg == 2) ? Wl : Wh;
        bf16_t* da = As3 + b * 8192 + wave * 512;
        bf16_t* db = Bs3 + b * 8192 + wave * 512;
        load_lds16(A + (size_t)(rowBase + sRow) * (2 * D_IN) + aOff + sC, da);
        load_lds16(A + (size_t)(rowBase + 128 + sRow) * (2 * D_IN) + aOff + sC,
                   da + 4096);
        load_lds16(Wp + (size_t)(colBase + sRow) * D_IN + k0 + sC, db);
        load_lds16(Wp + (size_t)(colBase + 128 + sRow) * D_IN + k0 + sC,
                   db + 4096);
    };

    // pipeline fill: tile0->buf0, tile1->buf1, drain, publish, preload frags0
    stage_tile(0, 0);
    stage_tile(1, 1);
    WAIT_VM0;
    BAR;
    READ_A4(af0, 0, 0); READ_A4(af0, 0, 1); READ_B4(bf0, 0);

    // 6x unrolled steady state: frag ping-pong (mod 2) x LDS rotation (mod 3).
    // Keep outer loop rolled; bodies use static buffer/frag indices (rule #20).
#pragma clang loop unroll(disable)
    for (int t = 0; t < NT; t += 6) {
        BODY(af0, bf0, af1, bf1, 1, 2, t + 2);
        BODY(af1, bf1, af0, bf0, 2, 0, t + 3);
        BODY(af0, bf0, af1, bf1, 0, 1, t + 4);
        BODY(af1, bf1, af0, bf0, 1, 2, t + 5);
        BODY(af0, bf0, af1, bf1, 2, 0, t + 6);
        BODY(af1, bf1, af0, bf0, 0, 1, t + 7);
    }

    // C/D: col = lane&15 (N dim), row = quad*4 + reg (M dim). NT stores: U is a
    // 134MB stream; keep it out of L3 so A stays resident.
#pragma unroll
    for (int mi = 0; mi < 8; ++mi)
#pragma unroll
        for (int ni = 0; ni < 4; ++ni) {
            const int col = colBase + wn * 64 + ni * 16 + m16;
            float* up = U + (size_t)(rowBase + wm * 128 + mi * 16 + quad * 4) * D_OUT
                          + col;
#pragma unroll
            for (int r = 0; r < 4; ++r)
                __builtin_nontemporal_store(acc[mi][ni][r], up + (size_t)r * D_OUT);
        }
}

// ---------- Kernel 3: per-row hyperbolic chain, out = Ascale*u + alpha*b (f32) ----------
__global__ __launch_bounds__(256) void pvfc_epilogue(
    const float* __restrict__ U, const float* __restrict__ bvec,
    float* __restrict__ out)
{
    __shared__ float red[12];
    const int row = blockIdx.x, tid = threadIdx.x;
    const int lane = tid & 63, wave = tid >> 6;

    const float* ur = U + (size_t)row * D_OUT + tid * 8;
    float u[8];
    { f32x4 a = __builtin_nontemporal_load((const f32x4*)ur);
      f32x4 c = __builtin_nontemporal_load((const f32x4*)(ur + 4));
      u[0]=a.x;u[1]=a.y;u[2]=a.z;u[3]=a.w;u[4]=c.x;u[5]=c.y;u[6]=c.z;u[7]=c.w; }
    float b[8];
    { const float* br = bvec + tid * 8;
      f32x4 a = *(const f32x4*)br, c = *(const f32x4*)(br + 4);
      b[0]=a.x;b[1]=a.y;b[2]=a.z;b[3]=a.w;b[4]=c.x;b[5]=c.y;b[6]=c.z;b[7]=c.w; }

    float su2 = 0.f, sub = 0.f, sbb = 0.f;
#pragma unroll
    for (int i = 0; i < 8; ++i) { su2 += u[i]*u[i]; sub += u[i]*b[i]; sbb += b[i]*b[i]; }
#pragma unroll
    for (int off = 32; off > 0; off >>= 1) {
        su2 += __shfl_down(su2, off, 64);
        sub += __shfl_down(sub, off, 64);
        sbb += __shfl_down(sbb, off, 64);
    }
    if (lane == 0) { red[wave] = su2; red[4 + wave] = sub; red[8 + wave] = sbb; }
    __syncthreads();
    su2 = red[0] + red[1] + red[2] + red[3];
    sub = red[4] + red[5] + red[6] + red[7];
    sbb = red[8] + red[9] + red[10] + red[11];

    // scalar chain (f32; verified against reference algebra; C=S=1)
    const float r0 = sqrtf(su2);
    const float t  = fminf(20.f / fmaxf(r0, EPSF), 1.f);    // proj_tan0
    const float rp = t * r0;
    const float coef_e = sinhf(rp) / fmaxf(rp, EPSF);       // exp0
    const float P  = coef_e * t;                            // y = P*u
    const float yn2 = P * P * su2;
    const float beta = 1.f / fmaxf(sqrtf(1.f + yn2), TINYF);
    const float c  = beta / (1.f + beta);                   // pt coef
    const float d  = P * sub;                               // <y,b>
    const float vn2   = sbb + c * d * d * (2.f + c * yn2);  // ||bt||^2
    const float dotxv = d * (1.f + c * yn2);                // <y,bt>
    const float g  = fmaxf(vn2 - dotxv * dotxv / (1.f + yn2), TINYF);
    const float rg = sqrtf(g);
    const float coef1 = beta / (1.f + beta);
    const float t1 = fmaxf(1.f + beta, TINYF);
    const float coef2 = -(beta * beta * beta) / (t1 * t1);
    const float lam = (1.f + beta) / fmaxf(beta, TINYF);
    const float z  = fminf(rg, 20.f);
    const float sc = (fabsf(z) < EPSF) ? (1.f + z * z * (1.f / 6.f))
                                       : (sinhf(z) / fmaxf(z, EPSF));
    const float L = lam * sc;
    const float alpha = L * coef1;                          // w = alpha*b + gamma*y
    const float gamma = L * (coef1 * c * d + coef2 * dotxv);
    const float wn2 = alpha * alpha * sbb + 2.f * alpha * gamma * d + gamma * gamma * yn2;
    const float bw  = 1.f / fmaxf(sqrtf(1.f + wn2), TINYF);
    const float xy  = alpha * d + gamma * yn2;
    const float coefg = coef1 * xy + (1.f - bw) / bw;       // gyro_add coef
    const float Ascale = P * (1.f + gamma + coefg);

    float* orow = out + (size_t)row * D_OUT + tid * 8;
    f32x4 o0, o1;
    o0.x = Ascale*u[0] + alpha*b[0]; o0.y = Ascale*u[1] + alpha*b[1];
    o0.z = Ascale*u[2] + alpha*b[2]; o0.w = Ascale*u[3] + alpha*b[3];
    o1.x = Ascale*u[4] + alpha*b[4]; o1.y = Ascale*u[5] + alpha*b[5];
    o1.z = Ascale*u[6] + alpha*b[6]; o1.w = Ascale*u[7] + alpha*b[7];
    __builtin_nontemporal_store(o0, (f32x4*)orow);
    __builtin_nontemporal_store(o1, (f32x4*)(orow + 4));
}

extern "C" void kernel_launch(void* const* d_in, const int* in_sizes, int n_in,
                              void* d_out, int out_size, void* d_ws, size_t ws_size,
                              hipStream_t stream)
{
    const float* x = (const float*)d_in[0];
    const float* W = (const float*)d_in[1];
    const float* b = (const float*)d_in[2];
    float* out = (float*)d_out;

    // ws layout: Wh (8 MiB) | Wl (8 MiB) | per-chunk { A [chunk][4096] bf16 (8KB/row),
    //                                                  U [chunk][2048] f32  (8KB/row) }
    bf16_t* Wh = (bf16_t*)d_ws;
    bf16_t* Wl = Wh + (size_t)D_OUT * D_IN;
    char*   rest = (char*)(Wl + (size_t)D_OUT * D_IN);
    const size_t wbytes = (size_t)D_OUT * D_IN * 2 * 2;           // 16 MiB
    const size_t avail  = (ws_size > wbytes) ? ws_size - wbytes : 0;
    int chunk = (int)((avail / 16384 / 256) * 256);               // rows, multiple of 256
    if (chunk <= 0) chunk = 256;
    if (chunk > N_ROWS) chunk = N_ROWS;

    bf16_t* Ap = (bf16_t*)rest;
    float*  U  = (float*)(rest + (size_t)chunk * (2 * D_IN) * 2);

    pvfc_wsplit<<<(D_OUT * D_IN) / (256 * 8), 256, 0, stream>>>(W, Wh, Wl);
    for (int r0 = 0; r0 < N_ROWS; r0 += chunk) {
        const int rows = (N_ROWS - r0 < chunk) ? (N_ROWS - r0) : chunk;
        pvfc_prologue<<<rows, 256, 0, stream>>>(x + (size_t)r0 * D_IN, Ap);
        pvfc_gemm<<<dim3(D_OUT / BN * (rows / BM)), 512, 0, stream>>>(Ap, Wh, Wl, U);
        pvfc_epilogue<<<rows, 256, 0, stream>>>(U, b, out + (size_t)r0 * D_OUT);
    }
}

// Round 8
// 601.961 us; speedup vs baseline: 1.1791x; 1.1791x over previous
//
#include <hip/hip_runtime.h>
#include <stdint.h>

typedef __bf16 bf16_t;
typedef __bf16 bf16x8 __attribute__((ext_vector_type(8)));
typedef float floatx4 __attribute__((ext_vector_type(4)));
typedef float f32x4 __attribute__((ext_vector_type(4)));  // for nontemporal builtins

#define N_ROWS 16384
#define D_IN   2048
#define D_OUT  2048
#define EPSF   1e-6f
#define TINYF  1e-15f

// GEMM geometry: 256x256 tile, BK=32, FUSED hi/lo segments, 8 waves,
// 2-deep LDS double buffer of {Ah,Al,Wh,Wl} units (64 KB each, 128 KiB total)
#define BM 256
#define BN 256
#define BK 32
#define NK 64   // 2048 / 32 k-steps (single fused K-pass)

// async global->LDS, 16B/lane; LDS base wave-uniform, lane*16 implicit
__device__ __forceinline__ void load_lds16(const void* g, void* l) {
    __builtin_amdgcn_global_load_lds(
        (const __attribute__((address_space(1))) unsigned int*)(const unsigned int*)g,
        (__attribute__((address_space(3))) unsigned int*)(unsigned int*)l,
        16, 0, 0);
}

// ---------- Kernel 0: split W (f32) into bf16 hi/lo planes ----------
__global__ __launch_bounds__(256) void pvfc_wsplit(
    const float* __restrict__ W, bf16_t* __restrict__ Wh, bf16_t* __restrict__ Wl)
{
    const size_t i = ((size_t)blockIdx.x * 256 + threadIdx.x) * 8;
    f32x4 a = *(const f32x4*)(W + i);
    f32x4 c = *(const f32x4*)(W + i + 4);
    float v[8] = {a.x, a.y, a.z, a.w, c.x, c.y, c.z, c.w};
    bf16x8 hv, lv;
#pragma unroll
    for (int j = 0; j < 8; ++j) {
        const bf16_t h = (bf16_t)v[j];
        hv[j] = h;
        lv[j] = (bf16_t)(v[j] - (float)h);
    }
    *(bf16x8*)(Wh + i) = hv;
    *(bf16x8*)(Wl + i) = lv;
}

// ---------- Kernel 1: v = asinh(||x||)/||x|| * x, split into bf16 hi/lo ----------
// A layout: [rows][4096] bf16 : cols 0..2047 = v_hi, 2048..4095 = v_lo
__global__ __launch_bounds__(256) void pvfc_prologue(
    const float* __restrict__ x, bf16_t* __restrict__ Ap)
{
    __shared__ float red[4];
    const int row = blockIdx.x, tid = threadIdx.x;
    const int lane = tid & 63, wave = tid >> 6;

    const float* xr = x + (size_t)row * D_IN + tid * 8;
    f32x4 a = __builtin_nontemporal_load((const f32x4*)xr);
    f32x4 c = __builtin_nontemporal_load((const f32x4*)(xr + 4));
    float v[8] = {a.x, a.y, a.z, a.w, c.x, c.y, c.z, c.w};

    float s = 0.f;
#pragma unroll
    for (int i = 0; i < 8; ++i) s += v[i] * v[i];
#pragma unroll
    for (int off = 32; off > 0; off >>= 1) s += __shfl_down(s, off, 64);
    if (lane == 0) red[wave] = s;
    __syncthreads();
    const float s2  = red[0] + red[1] + red[2] + red[3];
    const float nrm = sqrtf(s2);
    const float coef = asinhf(nrm) / fmaxf(nrm, EPSF);

    bf16x8 hv, lv;
#pragma unroll
    for (int j = 0; j < 8; ++j) {
        const float vi = coef * v[j];
        const bf16_t h = (bf16_t)vi;
        hv[j] = h;
        lv[j] = (bf16_t)(vi - (float)h);
    }
    bf16_t* ar = Ap + (size_t)row * (2 * D_IN);
    *(bf16x8*)(ar + tid * 8)         = hv;   // cached: gemm re-reads A via L3
    *(bf16x8*)(ar + D_IN + tid * 8)  = lv;
}

// ---------- Kernel 2: U = Ah.Wh^T + Al.Wh^T + Ah.Wl^T, FUSED single K-pass ----------
// Round-7 post-mortem: conflicts 0 but time unchanged -> LDS conflicts were not
// critical; FETCH 840MB @ 1.8TB/s sustained IS (5.8x over unique 145MB). Cause:
// 3 sequential segment passes re-staged Ah and Wh and re-fetched Ah from HBM
// after L3 eviction. Fused: per k0 stage {Ah,Al,Wh,Wl} once, accumulate all 3
// products (96 MFMA/wave) into the same acc. Staging -33%, LDS reads -33%
// (Ah frags reused in-register), A HBM stream single-pass.
// Body is long (~2400cyc) >> HBM latency -> 2-buffer vmcnt(0)+BAR drain is
// covered (round-4 best-measured pattern). Swizzle: round-7 chunk-XOR, both
// sides (verified conflicts=0). One barrier per body.
#define BAR __builtin_amdgcn_s_barrier()
#define SCHED_FENCE __builtin_amdgcn_sched_barrier(0)
#define WAIT_VM0   do { asm volatile("s_waitcnt vmcnt(0)" ::: "memory");   \
                        __builtin_amdgcn_sched_barrier(0); } while (0)

// LDS: Sh[buf][unit][256*32], unit 0:Ah 1:Al 2:Wh 3:Wl; elem offsets
#define UOFF(bb, unit) ((bb) * 32768 + (unit) * 8192)

// read 8 A-frags (128 rows of this wave's wm half) from unit u of buf bb
#define RD_A8(AF, bb, u)                                                       \
    _Pragma("unroll")                                                          \
    for (int mi = 0; mi < 8; ++mi)                                             \
        AF[mi] = *(const bf16x8*)&Sh[UOFF(bb, u) +                             \
                    (wm * 128 + mi * 16 + m16) * 32 + ((quad ^ swk) * 8)];
// read 4 B-frags (64 cols of this wave's wn quarter) from unit u of buf bb
#define RD_B4(BF, bb, u)                                                       \
    _Pragma("unroll")                                                          \
    for (int j = 0; j < 4; ++j)                                                \
        BF[j] = *(const bf16x8*)&Sh[UOFF(bb, u) +                              \
                    (wn * 64 + j * 16 + m16) * 32 + ((quad ^ swk) * 8)];
// one product: 8x4 = 32 MFMA into the shared accumulator
#define MFMA_P(AF, BF)                                                         \
    do {                                                                       \
        __builtin_amdgcn_s_setprio(1);                                         \
        _Pragma("unroll")                                                      \
        for (int i = 0; i < 8; ++i)                                            \
            _Pragma("unroll")                                                  \
            for (int j = 0; j < 4; ++j)                                        \
                acc[i][j] = __builtin_amdgcn_mfma_f32_16x16x32_bf16(           \
                    AF[i], BF[j], acc[i][j], 0, 0, 0);                         \
        __builtin_amdgcn_s_setprio(0);                                         \
    } while (0)

// body: compute k-step from buf bb; stage k-step t1 into buf nb; ONE barrier.
// Hazards: RAW: stage(t1->nb) drained by WAIT_VM0 before BAR; reads of nb in
// next body after BAR. WAR: nb's prior ds_reads completed in the previous body
// (lgkm-pinned before its MFMAs, which precede its end barrier).
#define BODY(bb, nb, t1)                                                       \
    do {                                                                       \
        stage_tile(t1, nb);                        /* 8 vmem, drains at end */ \
        SCHED_FENCE;                                                           \
        RD_B4(wfh, bb, 2); RD_A8(ah, bb, 0);                                   \
        SCHED_FENCE;                                                           \
        MFMA_P(ah, wfh);                           /* Ah.Wh */                 \
        SCHED_FENCE;                                                           \
        RD_A8(al, bb, 1);                                                      \
        SCHED_FENCE;                                                           \
        MFMA_P(al, wfh);                           /* Al.Wh */                 \
        SCHED_FENCE;                                                           \
        RD_B4(wfl, bb, 3);                                                     \
        SCHED_FENCE;                                                           \
        MFMA_P(ah, wfl);                           /* Ah.Wl */                 \
        WAIT_VM0;                                                              \
        BAR;                                                                   \
    } while (0)

__global__ __launch_bounds__(512, 2) void pvfc_gemm(
    const bf16_t* __restrict__ A,   // [rows][4096] hi|lo
    const bf16_t* __restrict__ Wh, const bf16_t* __restrict__ Wl, // [2048][2048]
    float* __restrict__ U)          // [rows][2048] f32
{
    __shared__ __align__(16) bf16_t Sh[2 * 4 * 8192];  // 128 KiB

    const int tid  = threadIdx.x;
    const int wave = tid >> 6, lane = tid & 63;
    const int bid  = blockIdx.x;
    const int colBase = (bid & 7) * BN;   // bid%8 == XCD: W panel L2-resident
    const int rowBase = (bid >> 3) * BM;

    const int wm = wave >> 2, wn = wave & 3;   // 2x4 wave grid, 128x64/wave
    const int m16 = lane & 15, quad = lane >> 4;
    const int swk = (m16 >> 1) & 3;            // read-side xor key (round-7, verified)

    floatx4 acc[8][4];
    bf16x8 ah[8], al[8], wfh[4], wfl[4];
    const floatx4 z = {0.f, 0.f, 0.f, 0.f};
#pragma unroll
    for (int i = 0; i < 8; ++i)
#pragma unroll
        for (int j = 0; j < 4; ++j) acc[i][j] = z;

    // stage one fused k-step {Ah,Al,Wh,Wl} (4 x 16KB) into buf b.
    // LDS dest linear; source column pre-swizzled (both-sides rule, round-7 key):
    // thread writes phys chunk tid&3 of row tid>>2 -> logical chunk ^((row>>1)&3).
    const int sRow = tid >> 2;                                  // 0..127
    const int sC   = (((tid & 3) ^ ((tid >> 3) & 3)) * 8);      // swizzled col
    auto stage_tile = [&](int tile, int b) {
        const int tt = tile < NK ? tile : NK - 1;  // tail clamp: never read
        const int k0 = tt * BK;
        bf16_t* base = Sh + b * 32768 + wave * 512;
        const bf16_t* a0 = A + (size_t)(rowBase + sRow) * (2 * D_IN) + k0 + sC;
        const bf16_t* a1 = A + (size_t)(rowBase + 128 + sRow) * (2 * D_IN) + k0 + sC;
        load_lds16(a0, base);                              // Ah rows 0..127
        load_lds16(a1, base + 4096);                       // Ah rows 128..255
        load_lds16(a0 + D_IN, base + 8192);                // Al rows 0..127
        load_lds16(a1 + D_IN, base + 8192 + 4096);         // Al rows 128..255
        const bf16_t* w0 = Wh + (size_t)(colBase + sRow) * D_IN + k0 + sC;
        const bf16_t* w1 = Wh + (size_t)(colBase + 128 + sRow) * D_IN + k0 + sC;
        load_lds16(w0, base + 16384);                      // Wh cols 0..127
        load_lds16(w1, base + 16384 + 4096);               // Wh cols 128..255
        const bf16_t* v0 = Wl + (size_t)(colBase + sRow) * D_IN + k0 + sC;
        const bf16_t* v1 = Wl + (size_t)(colBase + 128 + sRow) * D_IN + k0 + sC;
        load_lds16(v0, base + 24576);                      // Wl cols 0..127
        load_lds16(v1, base + 24576 + 4096);               // Wl cols 128..255
    };

    // pipeline fill: k-step 0 -> buf0, drain, publish
    stage_tile(0, 0);
    WAIT_VM0;
    BAR;

    // 2x unrolled steady state (static buf indices); outer loop rolled.
#pragma clang loop unroll(disable)
    for (int t = 0; t < NK; t += 2) {
        BODY(0, 1, t + 1);   // compute k-step t   (buf0), stage t+1 -> buf1
        BODY(1, 0, t + 2);   // compute k-step t+1 (buf1), stage t+2 -> buf0
    }

    // C/D: col = lane&15 (N dim), row = quad*4 + reg (M dim). NT stores: U is a
    // 134MB stream; keep it out of L3 so A stays resident.
#pragma unroll
    for (int mi = 0; mi < 8; ++mi)
#pragma unroll
        for (int ni = 0; ni < 4; ++ni) {
            const int col = colBase + wn * 64 + ni * 16 + m16;
            float* up = U + (size_t)(rowBase + wm * 128 + mi * 16 + quad * 4) * D_OUT
                          + col;
#pragma unroll
            for (int r = 0; r < 4; ++r)
                __builtin_nontemporal_store(acc[mi][ni][r], up + (size_t)r * D_OUT);
        }
}

// ---------- Kernel 3: per-row hyperbolic chain, out = Ascale*u + alpha*b (f32) ----------
__global__ __launch_bounds__(256) void pvfc_epilogue(
    const float* __restrict__ U, const float* __restrict__ bvec,
    float* __restrict__ out)
{
    __shared__ float red[12];
    const int row = blockIdx.x, tid = threadIdx.x;
    const int lane = tid & 63, wave = tid >> 6;

    const float* ur = U + (size_t)row * D_OUT + tid * 8;
    float u[8];
    { f32x4 a = __builtin_nontemporal_load((const f32x4*)ur);
      f32x4 c = __builtin_nontemporal_load((const f32x4*)(ur + 4));
      u[0]=a.x;u[1]=a.y;u[2]=a.z;u[3]=a.w;u[4]=c.x;u[5]=c.y;u[6]=c.z;u[7]=c.w; }
    float b[8];
    { const float* br = bvec + tid * 8;
      f32x4 a = *(const f32x4*)br, c = *(const f32x4*)(br + 4);
      b[0]=a.x;b[1]=a.y;b[2]=a.z;b[3]=a.w;b[4]=c.x;b[5]=c.y;b[6]=c.z;b[7]=c.w; }

    float su2 = 0.f, sub = 0.f, sbb = 0.f;
#pragma unroll
    for (int i = 0; i < 8; ++i) { su2 += u[i]*u[i]; sub += u[i]*b[i]; sbb += b[i]*b[i]; }
#pragma unroll
    for (int off = 32; off > 0; off >>= 1) {
        su2 += __shfl_down(su2, off, 64);
        sub += __shfl_down(sub, off, 64);
        sbb += __shfl_down(sbb, off, 64);
    }
    if (lane == 0) { red[wave] = su2; red[4 + wave] = sub; red[8 + wave] = sbb; }
    __syncthreads();
    su2 = red[0] + red[1] + red[2] + red[3];
    sub = red[4] + red[5] + red[6] + red[7];
    sbb = red[8] + red[9] + red[10] + red[11];

    // scalar chain (f32; verified against reference algebra; C=S=1)
    const float r0 = sqrtf(su2);
    const float t  = fminf(20.f / fmaxf(r0, EPSF), 1.f);    // proj_tan0
    const float rp = t * r0;
    const float coef_e = sinhf(rp) / fmaxf(rp, EPSF);       // exp0
    const float P  = coef_e * t;                            // y = P*u
    const float yn2 = P * P * su2;
    const float beta = 1.f / fmaxf(sqrtf(1.f + yn2), TINYF);
    const float c  = beta / (1.f + beta);                   // pt coef
    const float d  = P * sub;                               // <y,b>
    const float vn2   = sbb + c * d * d * (2.f + c * yn2);  // ||bt||^2
    const float dotxv = d * (1.f + c * yn2);                // <y,bt>
    const float g  = fmaxf(vn2 - dotxv * dotxv / (1.f + yn2), TINYF);
    const float rg = sqrtf(g);
    const float coef1 = beta / (1.f + beta);
    const float t1 = fmaxf(1.f + beta, TINYF);
    const float coef2 = -(beta * beta * beta) / (t1 * t1);
    const float lam = (1.f + beta) / fmaxf(beta, TINYF);
    const float z  = fminf(rg, 20.f);
    const float sc = (fabsf(z) < EPSF) ? (1.f + z * z * (1.f / 6.f))
                                       : (sinhf(z) / fmaxf(z, EPSF));
    const float L = lam * sc;
    const float alpha = L * coef1;                          // w = alpha*b + gamma*y
    const float gamma = L * (coef1 * c * d + coef2 * dotxv);
    const float wn2 = alpha * alpha * sbb + 2.f * alpha * gamma * d + gamma * gamma * yn2;
    const float bw  = 1.f / fmaxf(sqrtf(1.f + wn2), TINYF);
    const float xy  = alpha * d + gamma * yn2;
    const float coefg = coef1 * xy + (1.f - bw) / bw;       // gyro_add coef
    const float Ascale = P * (1.f + gamma + coefg);

    float* orow = out + (size_t)row * D_OUT + tid * 8;
    f32x4 o0, o1;
    o0.x = Ascale*u[0] + alpha*b[0]; o0.y = Ascale*u[1] + alpha*b[1];
    o0.z = Ascale*u[2] + alpha*b[2]; o0.w = Ascale*u[3] + alpha*b[3];
    o1.x = Ascale*u[4] + alpha*b[4]; o1.y = Ascale*u[5] + alpha*b[5];
    o1.z = Ascale*u[6] + alpha*b[6]; o1.w = Ascale*u[7] + alpha*b[7];
    __builtin_nontemporal_store(o0, (f32x4*)orow);
    __builtin_nontemporal_store(o1, (f32x4*)(orow + 4));
}

extern "C" void kernel_launch(void* const* d_in, const int* in_sizes, int n_in,
                              void* d_out, int out_size, void* d_ws, size_t ws_size,
                              hipStream_t stream)
{
    const float* x = (const float*)d_in[0];
    const float* W = (const float*)d_in[1];
    const float* b = (const float*)d_in[2];
    float* out = (float*)d_out;

    // ws layout: Wh (8 MiB) | Wl (8 MiB) | per-chunk { A [chunk][4096] bf16 (8KB/row),
    //                                                  U [chunk][2048] f32  (8KB/row) }
    bf16_t* Wh = (bf16_t*)d_ws;
    bf16_t* Wl = Wh + (size_t)D_OUT * D_IN;
    char*   rest = (char*)(Wl + (size_t)D_OUT * D_IN);
    const size_t wbytes = (size_t)D_OUT * D_IN * 2 * 2;           // 16 MiB
    const size_t avail  = (ws_size > wbytes) ? ws_size - wbytes : 0;
    int chunk = (int)((avail / 16384 / 256) * 256);               // rows, multiple of 256
    if (chunk <= 0) chunk = 256;
    if (chunk > N_ROWS) chunk = N_ROWS;

    bf16_t* Ap = (bf16_t*)rest;
    float*  U  = (float*)(rest + (size_t)chunk * (2 * D_IN) * 2);

    pvfc_wsplit<<<(D_OUT * D_IN) / (256 * 8), 256, 0, stream>>>(W, Wh, Wl);
    for (int r0 = 0; r0 < N_ROWS; r0 += chunk) {
        const int rows = (N_ROWS - r0 < chunk) ? (N_ROWS - r0) : chunk;
        pvfc_prologue<<<rows, 256, 0, stream>>>(x + (size_t)r0 * D_IN, Ap);
        pvfc_gemm<<<dim3(D_OUT / BN * (rows / BM)), 512, 0, stream>>>(Ap, Wh, Wl, U);
        pvfc_epilogue<<<rows, 256, 0, stream>>>(U, b, out + (size_t)r0 * D_OUT);
    }
}